// Round 3
// baseline (1187.150 us; speedup 1.0000x reference)
//
#include <hip/hip_runtime.h>
#include <hip/hip_cooperative_groups.h>

namespace cg = cooperative_groups;

// ClauseInferModule: C=16, B=64, G=2048, S=8, L=4, 3 steps.
// Single cooperative kernel, grid=1024 blocks (4/CU, co-resident), 256 thr.
// Work in w-units: w = v * (1000/ln2). Then exp((a-b)/gamma) == exp2(wa-wb)
// and gamma*ln(sum) == log2(sum) EXACTLY (K*gamma = log2(e)) -> raw v_exp/v_log,
// no argument multiplies. Renorm divisions are pure scales -> unit-independent.
// Per step: clause phase (q in registers, m2 atomic) -> grid.sync ->
// merge phase (re-read src coalesced, s3, m3 atomic) -> grid.sync.
// Last step keeps s3 in registers; final scale by 1/max(m3,1) fused into the
// output write. softand's renorm is a provable no-op (R<=1 => softand<1).
// where(m>1,s/m,s) == s/max(m,1) exactly.

namespace {
constexpr int C = 16, B = 64, G = 2048, S = 8, L = 4;
constexpr int STEPS = 3;
constexpr int N  = C * B * G;
constexpr int BG = B * G;
constexpr float KF  = 1442.6950408889634f;    // 1000/ln2 : real -> w
constexpr float RKF = 6.9314718055994531e-4f; // ln2/1000 : w -> real
}

#define GAMMA 0.001f
#define INVG  1000.0f

// Monotone float->uint key: unsigned atomicMax == float max. key identity = 0.
__device__ __forceinline__ unsigned f2key(float f) {
    unsigned b = __float_as_uint(f);
    return (b & 0x80000000u) ? ~b : (b | 0x80000000u);
}
__device__ __forceinline__ float key2f(unsigned k) {
    return (k & 0x80000000u) ? __uint_as_float(k & 0x7fffffffu)
                             : __uint_as_float(~k);
}

// mk layout: [0..47] m2 (C per step), [48..50] m3 per step, [51] key(1.0) (fallback)
__global__ __launch_bounds__(256, 4) void k_fused(const float* __restrict__ x,
                                                  const int* __restrict__ I,
                                                  float* __restrict__ Rw,
                                                  float* __restrict__ outp,
                                                  unsigned* __restrict__ mk) {
    cg::grid_group grid = cg::this_grid();
    __shared__ float lds[2][G];       // 2 x 8 KB double buffer (w-units, scaled)
    __shared__ float wmax[4];
    __shared__ float sh_bcast;

    const int blk = blockIdx.x, tid = threadIdx.x;
    const int bchunk = blk & 7, gtile = (blk >> 3) & 7, c = blk >> 6;
    const int g = gtile * 256 + tid, b0 = bchunk * 8;

    // I indices register-cached ONCE for all 3 steps x 8 b's.
    const int4* Ib = (const int4*)(I + (size_t)(c * G + g) * (S * L));
    int4 ix[S];
#pragma unroll
    for (int s = 0; s < S; ++s) ix[s] = Ib[s];

    float stagescale = KF;            // step 0: x (real) -> w; later: m3 renorm in w
    float q[8], s3[8];

#pragma unroll
    for (int step = 0; step < STEPS; ++step) {
        const float* src = (step == 0) ? x : Rw;
        const int rbase  = (step == 0) ? b0 : (c * B + b0);

        // ---- clause phase: 8 b's, double-buffered LDS row staging ----
        const float4* r4 = (const float4*)(src + (size_t)rbase * G);
        float4 pre0 = r4[tid], pre1 = r4[tid + 256];
        float lmax = -3.0e38f;
        for (int bi = 0; bi < 8; ++bi) {
            int buf = bi & 1;
            __syncthreads();                       // reads of lds[buf] (bi-2) done
            float4* l4 = (float4*)lds[buf];
            float4 a0 = pre0, a1 = pre1;
            a0.x *= stagescale; a0.y *= stagescale; a0.z *= stagescale; a0.w *= stagescale;
            a1.x *= stagescale; a1.y *= stagescale; a1.z *= stagescale; a1.w *= stagescale;
            l4[tid] = a0; l4[tid + 256] = a1;
            if (bi < 7) {
                const float4* rn = (const float4*)(src + (size_t)(rbase + bi + 1) * G);
                pre0 = rn[tid]; pre1 = rn[tid + 256];
            }
            __syncthreads();                       // staging visible
            const float* row = lds[buf];
            float P[S];
#pragma unroll
            for (int s = 0; s < S; ++s) {
                int4 iv = ix[s];
                float w0 = row[iv.x], w1 = row[iv.y], w2 = row[iv.z], w3 = row[iv.w];
                float wm = fminf(fminf(w0, w1), fminf(w2, w3));
                float sum = exp2f(wm - w0) + exp2f(wm - w1)
                          + exp2f(wm - w2) + exp2f(wm - w3);
                P[s] = wm - log2f(sum);            // softand (w-units); renorm no-op
            }
            float pm = P[0];
#pragma unroll
            for (int s = 1; s < S; ++s) pm = fmaxf(pm, P[s]);
            float ssum = 0.0f;
#pragma unroll
            for (int s = 0; s < S; ++s) ssum += exp2f(P[s] - pm);
            float qv = pm + log2f(ssum);           // softor over S (w-units)
            q[bi] = qv;
            lmax = fmaxf(lmax, qv);
        }
        // block max -> one m2 atomic per block
        {
            float m = lmax;
            for (int off = 32; off; off >>= 1) m = fmaxf(m, __shfl_down(m, off));
            if ((tid & 63) == 0) wmax[tid >> 6] = m;
            __syncthreads();
            if (tid == 0) {
                float mm = fmaxf(fmaxf(wmax[0], wmax[1]), fmaxf(wmax[2], wmax[3]));
                atomicMax(mk + step * C + c, f2key(mm));
            }
        }
        grid.sync();

        // ---- merge phase: own elements only (read set == write set) ----
        if (tid == 0) sh_bcast = key2f(atomicMax(mk + step * C + c, 0u));
        __syncthreads();
        float qden = 1.0f / fmaxf(sh_bcast * RKF, 1.0f);
        float lm3 = -3.0e38f;
#pragma unroll
        for (int bi = 0; bi < 8; ++bi) {
            size_t off = (size_t)(rbase + bi) * G + g;
            float rv = src[off] * stagescale;      // same scaled value as staged
            float qv = q[bi] * qden;
            float hi = fmaxf(rv, qv), lo = fminf(rv, qv);
            float sv = hi + log2f(1.0f + exp2f(lo - hi));  // softor2 (w-units)
            s3[bi] = sv;
            lm3 = fmaxf(lm3, sv);
            if (step < STEPS - 1) Rw[(size_t)(c * B + b0 + bi) * G + g] = sv;
        }
        {
            float m = lm3;
            for (int off = 32; off; off >>= 1) m = fmaxf(m, __shfl_down(m, off));
            __syncthreads();                       // wmax reuse guard
            if ((tid & 63) == 0) wmax[tid >> 6] = m;
            __syncthreads();
            if (tid == 0) {
                float mm = fmaxf(fmaxf(wmax[0], wmax[1]), fmaxf(wmax[2], wmax[3]));
                atomicMax(mk + 3 * C + step, f2key(mm));
            }
        }
        __threadfence();                           // release Rw before grid barrier
        grid.sync();
        __threadfence();                           // acquire (L1 inv) for Rw reads
        if (tid == 0) sh_bcast = key2f(atomicMax(mk + 3 * C + step, 0u));
        __syncthreads();
        stagescale = 1.0f / fmaxf(sh_bcast * RKF, 1.0f);   // next step's m3 renorm
    }

    // final: out_real = s3_w * denr / K
    float fs = stagescale * RKF;
#pragma unroll
    for (int bi = 0; bi < 8; ++bi)
        outp[(size_t)(c * B + b0 + bi) * G + g] = s3[bi] * fs;
}

// ======================= fallback (round-1 proven path) ======================
__global__ __launch_bounds__(256) void fb_init(unsigned* __restrict__ mkeys) {
    int t = threadIdx.x;
    if (t < 52) mkeys[t] = (t == 51) ? 0xBF800000u : 0u;
}

__global__ __launch_bounds__(256) void fb_clause(const float* __restrict__ src, int bcast,
                                                 const int* __restrict__ I,
                                                 float* __restrict__ q,
                                                 unsigned* __restrict__ m2k,
                                                 const unsigned* __restrict__ m3prev) {
    __shared__ float lds[2][G];
    __shared__ float wmax[4];
    int blk = blockIdx.x;
    int bchunk = blk & 7, gtile = (blk >> 3) & 7, c = blk >> 6;
    int tid = threadIdx.x, g = gtile * 256 + tid;

    const int4* Ib = (const int4*)(I + (size_t)(c * G + g) * (S * L));
    int4 ix[S];
#pragma unroll
    for (int s = 0; s < S; ++s) ix[s] = Ib[s];

    float denr = 1.0f / fmaxf(key2f(*m3prev), 1.0f);
    int b0 = bchunk * 8;
    const float4* r4 = (const float4*)(src + (size_t)(bcast ? b0 : (c * B + b0)) * G);
    float4 pre0 = r4[tid], pre1 = r4[tid + 256];
    float lmax = -3.0e38f;
    for (int bi = 0; bi < 8; ++bi) {
        int b = b0 + bi, buf = bi & 1;
        __syncthreads();
        float4* l4 = (float4*)lds[buf];
        float4 a0 = pre0, a1 = pre1;
        a0.x *= denr; a0.y *= denr; a0.z *= denr; a0.w *= denr;
        a1.x *= denr; a1.y *= denr; a1.z *= denr; a1.w *= denr;
        l4[tid] = a0; l4[tid + 256] = a1;
        if (bi < 7) {
            const float4* rn = (const float4*)(src + (size_t)(bcast ? (b + 1) : (c * B + b + 1)) * G);
            pre0 = rn[tid]; pre1 = rn[tid + 256];
        }
        __syncthreads();
        const float* row = lds[buf];
        float p[S];
#pragma unroll
        for (int s = 0; s < S; ++s) {
            int4 iv = ix[s];
            float v0 = row[iv.x], v1 = row[iv.y], v2 = row[iv.z], v3 = row[iv.w];
            float vmin = fminf(fminf(v0, v1), fminf(v2, v3));
            float sum = __expf((vmin - v0) * INVG) + __expf((vmin - v1) * INVG)
                      + __expf((vmin - v2) * INVG) + __expf((vmin - v3) * INVG);
            p[s] = vmin - GAMMA * __logf(sum);
        }
        float pm = p[0];
#pragma unroll
        for (int s = 1; s < S; ++s) pm = fmaxf(pm, p[s]);
        float sum2 = 0.0f;
#pragma unroll
        for (int s = 0; s < S; ++s) sum2 += __expf((p[s] - pm) * INVG);
        float s2 = pm + GAMMA * __logf(sum2);
        q[(size_t)(c * B + b) * G + g] = s2;
        lmax = fmaxf(lmax, s2);
    }
    float m = lmax;
    for (int off = 32; off; off >>= 1) m = fmaxf(m, __shfl_down(m, off));
    int lane = tid & 63, w = tid >> 6;
    if (lane == 0) wmax[w] = m;
    __syncthreads();
    if (tid == 0) {
        float mm = fmaxf(fmaxf(wmax[0], wmax[1]), fmaxf(wmax[2], wmax[3]));
        atomicMax(m2k + c, f2key(mm));
    }
}

__global__ __launch_bounds__(256) void fb_merge(const float* __restrict__ src, int bcast,
                                                float* __restrict__ R,
                                                const float* __restrict__ q,
                                                const unsigned* __restrict__ m2k,
                                                const unsigned* __restrict__ m3prev,
                                                unsigned* __restrict__ m3out) {
    __shared__ float wmax[4];
    int idx = blockIdx.x * 256 + threadIdx.x;
    int c = idx >> 15;
    float denr = 1.0f / fmaxf(key2f(*m3prev), 1.0f);
    float qden = 1.0f / fmaxf(key2f(m2k[c]), 1.0f);
    int ridx = bcast ? (idx & (BG / 4 - 1)) : idx;
    float4 r4 = ((const float4*)src)[ridx];
    float4 q4 = ((const float4*)q)[idx];
    float rr[4] = {r4.x, r4.y, r4.z, r4.w};
    float qq[4] = {q4.x, q4.y, q4.z, q4.w};
    float lm = -3.0e38f;
#pragma unroll
    for (int i = 0; i < 4; ++i) {
        float rv = rr[i] * denr, qv = qq[i] * qden;
        float hi = fmaxf(rv, qv), lo = fminf(rv, qv);
        float sv = hi + GAMMA * __logf(1.0f + __expf((lo - hi) * INVG));
        rr[i] = sv; lm = fmaxf(lm, sv);
    }
    ((float4*)R)[idx] = make_float4(rr[0], rr[1], rr[2], rr[3]);
    for (int off = 32; off; off >>= 1) lm = fmaxf(lm, __shfl_down(lm, off));
    int lane = threadIdx.x & 63, w = threadIdx.x >> 6;
    if (lane == 0) wmax[w] = lm;
    __syncthreads();
    if (threadIdx.x == 0) {
        float mm = fmaxf(fmaxf(wmax[0], wmax[1]), fmaxf(wmax[2], wmax[3]));
        atomicMax(m3out, f2key(mm));
    }
}

__global__ __launch_bounds__(256) void fb_scale(float* __restrict__ R,
                                                const unsigned* __restrict__ m3k) {
    float denr = 1.0f / fmaxf(key2f(*m3k), 1.0f);
    int idx = blockIdx.x * 256 + threadIdx.x;
    float4 r = ((float4*)R)[idx];
    r.x *= denr; r.y *= denr; r.z *= denr; r.w *= denr;
    ((float4*)R)[idx] = r;
}

extern "C" void kernel_launch(void* const* d_in, const int* in_sizes, int n_in,
                              void* d_out, int out_size, void* d_ws, size_t ws_size,
                              hipStream_t stream) {
    const float* x = (const float*)d_in[0];   // (B, G) fp32
    const int*   I = (const int*)d_in[1];     // (C, G, S, L) int32
    float* out = (float*)d_out;               // (C, B, G) fp32

    float* Rw = (float*)d_ws;                                               // N floats
    unsigned* mk = (unsigned*)((char*)d_ws + (size_t)N * sizeof(float));    // 64 uints

    hipMemsetAsync(mk, 0, 64 * sizeof(unsigned), stream);

    void* args[] = {(void*)&x, (void*)&I, (void*)&Rw, (void*)&out, (void*)&mk};
    hipError_t err = hipLaunchCooperativeKernel((const void*)k_fused,
                                                dim3(C * 8 * 8), dim3(256),
                                                args, 0, stream);
    if (err != hipSuccess) {
        // fallback: proven multi-dispatch path (round-1)
        float* q = Rw;
        fb_init<<<1, 64, 0, stream>>>(mk);
        for (int step = 0; step < STEPS; ++step) {
            unsigned* m2k = mk + step * C;
            unsigned* m3out = mk + 48 + step;
            const unsigned* m3prev = (step == 0) ? (mk + 51) : (mk + 48 + step - 1);
            const float* src = (step == 0) ? x : out;
            int bcast = (step == 0) ? 1 : 0;
            fb_clause<<<C * 8 * 8, 256, 0, stream>>>(src, bcast, I, q, m2k, m3prev);
            fb_merge<<<N / 4 / 256, 256, 0, stream>>>(src, bcast, out, q, m2k, m3prev, m3out);
        }
        fb_scale<<<N / 4 / 256, 256, 0, stream>>>(out, mk + 48 + STEPS - 1);
    }
}

// Round 4
// 218.457 us; speedup vs baseline: 5.4342x; 5.4342x over previous
//
#include <hip/hip_runtime.h>

// ClauseInferModule: C=16, B=64, G=2048, S=8, L=4, 3 steps.
// Multi-dispatch (graph-friendly), w-units: w = v * (1000/ln2), so
// exp((a-b)/gamma) == exp2(wa-wb) and gamma*ln(sum) == log2(sum) EXACTLY.
// Per step:
//   k_clause: block=(c, gtile 256, bchunk 8). I register-cached (32 idx/thread),
//             two R rows staged per barrier pair (16.4 KB LDS), gathers from LDS.
//             Emits q (w-units, raw softor_S of softand_L) + per-clause max m2.
//             softand renorm is a provable no-op (R<=1 invariant => softand<1).
//   k_merge:  s3 = softor2(src*ss, q/max(m2,1)); writes w-units R to d_out,
//             accumulates global max m3. m3-renorm of step k is folded into
//             step k+1's staging scale (and the final k_scale).
//   k_scale:  in-place out *= RKF/max(m3,1)  (w -> real units).
// where(m>1,s/m,s) == s/max(m,1) exactly (division by 1.0 is exact).

namespace {
constexpr int C = 16, B = 64, G = 2048, S = 8, L = 4;
constexpr int STEPS = 3;
constexpr int N  = C * B * G;
constexpr int BG = B * G;
constexpr float KF  = 1442.6950408889634f;    // 1000/ln2 : real -> w
constexpr float RKF = 6.9314718055994531e-4f; // ln2/1000 : w -> real
}

// Monotone float->uint key: unsigned atomicMax == float max; identity = 0.
__device__ __forceinline__ unsigned f2key(float f) {
    unsigned b = __float_as_uint(f);
    return (b & 0x80000000u) ? ~b : (b | 0x80000000u);
}
__device__ __forceinline__ float key2f(unsigned k) {
    return (k & 0x80000000u) ? __uint_as_float(k & 0x7fffffffu)
                             : __uint_as_float(~k);
}

// mk layout: [0..47] m2 (C per step), [48..50] m3 per step. memset-0 = identity.

// grid = C*8*8 = 1024 blocks, 256 threads.
__global__ __launch_bounds__(256) void k_clause(const float* __restrict__ src, int step0,
                                                const int* __restrict__ I,
                                                float* __restrict__ q,
                                                unsigned* __restrict__ m2k,
                                                const unsigned* __restrict__ m3prev) {
    __shared__ float lds[2][G];     // two staged rows (w-units, scaled)
    __shared__ float wmax[4];

    const int blk = blockIdx.x, tid = threadIdx.x;
    const int bchunk = blk & 7, gtile = (blk >> 3) & 7, c = blk >> 6;
    const int g = gtile * 256 + tid, b0 = bchunk * 8;

    // register-cache this thread's 32 indices (reused for all 8 b's)
    const int4* Ib = (const int4*)(I + (size_t)(c * G + g) * (S * L));
    int4 ix[S];
#pragma unroll
    for (int s = 0; s < S; ++s) ix[s] = Ib[s];

    // staging scale: step0: real->w; else m3prev renorm (src already w-units)
    const float ss = step0 ? KF : 1.0f / fmaxf(key2f(*m3prev) * RKF, 1.0f);
    const int rbase = step0 ? b0 : (c * B + b0);

    // prefetch rows 0,1
    const float4* r0 = (const float4*)(src + (size_t)rbase * G);
    const float4* r1 = (const float4*)(src + (size_t)(rbase + 1) * G);
    float4 pa0 = r0[tid], pa1 = r0[tid + 256];
    float4 pb0 = r1[tid], pb1 = r1[tid + 256];

    float lmax = -3.0e38f;
    for (int bi = 0; bi < 8; bi += 2) {
        __syncthreads();                       // prior gathers on lds done
        float4* l0 = (float4*)lds[0];
        float4* l1 = (float4*)lds[1];
        float4 a;
        a = pa0; a.x *= ss; a.y *= ss; a.z *= ss; a.w *= ss; l0[tid] = a;
        a = pa1; a.x *= ss; a.y *= ss; a.z *= ss; a.w *= ss; l0[tid + 256] = a;
        a = pb0; a.x *= ss; a.y *= ss; a.z *= ss; a.w *= ss; l1[tid] = a;
        a = pb1; a.x *= ss; a.y *= ss; a.z *= ss; a.w *= ss; l1[tid + 256] = a;
        if (bi < 6) {                          // prefetch next pair
            const float4* n0 = (const float4*)(src + (size_t)(rbase + bi + 2) * G);
            const float4* n1 = (const float4*)(src + (size_t)(rbase + bi + 3) * G);
            pa0 = n0[tid]; pa1 = n0[tid + 256];
            pb0 = n1[tid]; pb1 = n1[tid + 256];
        }
        __syncthreads();                       // staging visible

#pragma unroll
        for (int h = 0; h < 2; ++h) {
            const float* row = lds[h];
            float P[S];
#pragma unroll
            for (int s = 0; s < S; ++s) {
                int4 iv = ix[s];
                float w0 = row[iv.x], w1 = row[iv.y], w2 = row[iv.z], w3 = row[iv.w];
                float wm = fminf(fminf(w0, w1), fminf(w2, w3));
                float sum = exp2f(wm - w0) + exp2f(wm - w1)
                          + exp2f(wm - w2) + exp2f(wm - w3);
                P[s] = wm - log2f(sum);        // softand (w-units); renorm no-op
            }
            float pm = P[0];
#pragma unroll
            for (int s = 1; s < S; ++s) pm = fmaxf(pm, P[s]);
            float ssum = 0.0f;
#pragma unroll
            for (int s = 0; s < S; ++s) ssum += exp2f(P[s] - pm);
            float qv = pm + log2f(ssum);       // softor over S (w-units)
            q[(size_t)(c * B + b0 + bi + h) * G + g] = qv;
            lmax = fmaxf(lmax, qv);
        }
    }

    // block max -> one m2 atomic per block
    float m = lmax;
    for (int off = 32; off; off >>= 1) m = fmaxf(m, __shfl_down(m, off));
    if ((tid & 63) == 0) wmax[tid >> 6] = m;
    __syncthreads();
    if (tid == 0) {
        float mm = fmaxf(fmaxf(wmax[0], wmax[1]), fmaxf(wmax[2], wmax[3]));
        atomicMax(m2k + c, f2key(mm));
    }
}

// grid = 1024 blocks, 2 float4 per thread (block spans 512 f4, never straddles c).
__global__ __launch_bounds__(256) void k_merge(const float* __restrict__ src, int step0,
                                               float* __restrict__ R,
                                               const float* __restrict__ q,
                                               const unsigned* __restrict__ m2k,
                                               const unsigned* __restrict__ m3prev,
                                               unsigned* __restrict__ m3out) {
    __shared__ float wmax[4];
    const int tid = threadIdx.x;
    const int c = blockIdx.x >> 6;             // 64 blocks per clause
    const float ss = step0 ? KF : 1.0f / fmaxf(key2f(*m3prev) * RKF, 1.0f);
    const float qden = 1.0f / fmaxf(key2f(m2k[c]) * RKF, 1.0f);

    float lm = -3.0e38f;
#pragma unroll
    for (int u = 0; u < 2; ++u) {
        int idx = blockIdx.x * 512 + u * 256 + tid;           // float4 index
        int ridx = step0 ? (idx & (BG / 4 - 1)) : idx;
        float4 r4 = ((const float4*)src)[ridx];
        float4 q4 = ((const float4*)q)[idx];
        float rr[4] = {r4.x, r4.y, r4.z, r4.w};
        float qq[4] = {q4.x, q4.y, q4.z, q4.w};
#pragma unroll
        for (int i = 0; i < 4; ++i) {
            float rv = rr[i] * ss;
            float qv = qq[i] * qden;
            float hi = fmaxf(rv, qv), lo = fminf(rv, qv);
            float sv = hi + log2f(1.0f + exp2f(lo - hi));     // softor2 (w-units)
            rr[i] = sv;
            lm = fmaxf(lm, sv);
        }
        ((float4*)R)[idx] = make_float4(rr[0], rr[1], rr[2], rr[3]);
    }

    for (int off = 32; off; off >>= 1) lm = fmaxf(lm, __shfl_down(lm, off));
    if ((tid & 63) == 0) wmax[tid >> 6] = lm;
    __syncthreads();
    if (tid == 0) {
        float mm = fmaxf(fmaxf(wmax[0], wmax[1]), fmaxf(wmax[2], wmax[3]));
        atomicMax(m3out, f2key(mm));
    }
}

// in-place: out(w-units) -> real, scaled by final m3 renorm.
__global__ __launch_bounds__(256) void k_scale(float* __restrict__ R,
                                               const unsigned* __restrict__ m3k) {
    float fs = RKF / fmaxf(key2f(*m3k) * RKF, 1.0f);
    int idx = blockIdx.x * 256 + threadIdx.x;
    float4 r = ((float4*)R)[idx];
    r.x *= fs; r.y *= fs; r.z *= fs; r.w *= fs;
    ((float4*)R)[idx] = r;
}

extern "C" void kernel_launch(void* const* d_in, const int* in_sizes, int n_in,
                              void* d_out, int out_size, void* d_ws, size_t ws_size,
                              hipStream_t stream) {
    const float* x = (const float*)d_in[0];   // (B, G) fp32
    const int*   I = (const int*)d_in[1];     // (C, G, S, L) int32
    float* out = (float*)d_out;               // (C, B, G) fp32 (w-units until k_scale)

    float* q = (float*)d_ws;                                               // N floats
    unsigned* mk = (unsigned*)((char*)d_ws + (size_t)N * sizeof(float));   // 64 uints

    hipMemsetAsync(mk, 0, 64 * sizeof(unsigned), stream);

    for (int step = 0; step < STEPS; ++step) {
        int step0 = (step == 0);
        const float* src = step0 ? x : out;
        unsigned* m2k = mk + step * C;
        unsigned* m3out = mk + 48 + step;
        const unsigned* m3prev = mk + 48 + (step ? step - 1 : 0);  // unused when step0
        k_clause<<<C * 8 * 8, 256, 0, stream>>>(src, step0, I, q, m2k, m3prev);
        k_merge<<<C * 8 * 8, 256, 0, stream>>>(src, step0, out, q, m2k, m3prev, m3out);
    }
    k_scale<<<N / 4 / 256, 256, 0, stream>>>(out, mk + 48 + STEPS - 1);
}